// Round 7
// baseline (20947.198 us; speedup 1.0000x reference)
//
#include <hip/hip_runtime.h>

#define TSTEPS 512
#define BATCH  64
#define FEAT   512
#define HID    1024
#define NWG    256
#define NTHR   256
#define AGENT  __HIP_MEMORY_SCOPE_AGENT

typedef _Float16 half8_t  __attribute__((ext_vector_type(8)));
typedef _Float16 half4_t  __attribute__((ext_vector_type(4)));
typedef float    float4_t __attribute__((ext_vector_type(4)));

__device__ __forceinline__ float sigf(float x)      { return 1.0f / (1.0f + __expf(-x)); }
__device__ __forceinline__ float tanh_fast(float x) { return 2.0f / (1.0f + __expf(-2.0f * x)) - 1.0f; }

// x[b][t][f] fp32 -> xT[t][b][f] fp16   (round-0 proven)
__global__ void xpose_kernel(const float* __restrict__ x, _Float16* __restrict__ xT) {
    int idx = blockIdx.x * NTHR + threadIdx.x;   // over B*T*F/4
    int f4 = idx & 127;                          // F/4 = 128
    int bt = idx >> 7;                           // b*T + t
    int t = bt & (TSTEPS - 1);
    int b = bt >> 9;
    float4_t v = ((const float4_t*)x)[idx];
    half4_t h;
    h.x = (_Float16)v.x; h.y = (_Float16)v.y; h.z = (_Float16)v.z; h.w = (_Float16)v.w;
    *(half4_t*)(xT + (size_t)(t * BATCH + b) * FEAT + f4 * 4) = h;
}

// bar layout (words, all zero-init, all monotone):
// [0]=gen  [32]=root  [64+32g]=line[g]  [512+32x]=crewcnt[x]
// [1024+32x]=epoch[x] [2048+32x]=lcnt[x]  [3072]=root2

// Step-1 barrier: round-5 proven full path (everyone release-arrives;
// delegated single inv per XCD; epoch publish). Doubles as census fence.
__device__ __forceinline__ void grid_barrier_full(unsigned* bar, int line_id, unsigned step,
                                                  unsigned my_slot, unsigned my_xcd) {
    __syncthreads();
    if (threadIdx.x == 0) {
        unsigned* gen   = bar;
        unsigned* root  = bar + 32;
        unsigned* line  = bar + 64 + 32 * line_id;
        unsigned* epoch = bar + 1024 + 32 * my_xcd;
        unsigned old = __hip_atomic_fetch_add(line, 1u, __ATOMIC_RELEASE, AGENT);
        if (old == 32u * step - 1u) {
            unsigned r = __hip_atomic_fetch_add(root, 1u, __ATOMIC_RELEASE, AGENT);
            if (r == 8u * step - 1u)
                __hip_atomic_store(gen, step, __ATOMIC_RELEASE, AGENT);
        }
        while (__hip_atomic_load(gen, __ATOMIC_RELAXED, AGENT) < step)
            __builtin_amdgcn_s_sleep(1);
        if (my_slot == 0) {
            __builtin_amdgcn_fence(__ATOMIC_ACQUIRE, "agent");  // one inv per XCD
            __hip_atomic_store(epoch, step, __ATOMIC_RELEASE, AGENT);
        } else {
            while (__hip_atomic_load(epoch, __ATOMIC_RELAXED, AGENT) < step)
                __builtin_amdgcn_s_sleep(1);
        }
    }
    __syncthreads();
    asm volatile("" ::: "memory");
}

// Slim barrier (steps >= 2): ONE wbl2 per XCD per step instead of 32.
// Dedicated counters, trivial invariants, no producer/consumer cycles:
//   peers:  relaxed add lcnt[xcd]  (h stores already complete in local L2
//           via __syncthreads' vmcnt drain) -> poll epoch[xcd] >= step.
//   leader: poll lcnt[xcd] >= (crewN-1)*sstep  (all local peers arrived)
//           -> release add root2   (ONE buffer_wbl2: flushes the WHOLE local
//              L2, i.e. all 32 WGs' dirty h lines, in one walk)
//           -> poll root2 >= nxcd*sstep  (all XCDs flushed; root2 IS the gen)
//           -> acquire fence (ONE buffer_inv per XCD)
//           -> release store epoch[xcd] = step (publishes inv completion).
// Read-side discipline (plain loads, leader-only inv, L1 streaming eviction)
// is bit-identical to round 5, which passed.
__device__ __forceinline__ void grid_barrier_slim(unsigned* bar, unsigned step,
                                                  unsigned my_slot, unsigned my_xcd,
                                                  unsigned crewN, unsigned nxcd) {
    __syncthreads();                        // drains all waves' vmem to local L2
    if (threadIdx.x == 0) {
        unsigned* epoch = bar + 1024 + 32 * my_xcd;
        unsigned* lcnt  = bar + 2048 + 32 * my_xcd;
        unsigned* root2 = bar + 3072;
        unsigned sstep = step - 1u;         // slim-step index: 1, 2, ...
        if (my_slot != 0) {
            __hip_atomic_fetch_add(lcnt, 1u, __ATOMIC_RELAXED, AGENT);
            while (__hip_atomic_load(epoch, __ATOMIC_RELAXED, AGENT) < step)
                __builtin_amdgcn_s_sleep(1);
        } else {
            while (__hip_atomic_load(lcnt, __ATOMIC_RELAXED, AGENT) < (crewN - 1u) * sstep)
                __builtin_amdgcn_s_sleep(1);
            __hip_atomic_fetch_add(root2, 1u, __ATOMIC_RELEASE, AGENT);   // ONE wbl2/XCD
            while (__hip_atomic_load(root2, __ATOMIC_RELAXED, AGENT) < nxcd * sstep)
                __builtin_amdgcn_s_sleep(1);
            __builtin_amdgcn_fence(__ATOMIC_ACQUIRE, "agent");            // ONE inv/XCD
            __hip_atomic_store(epoch, step, __ATOMIC_RELEASE, AGENT);
        }
    }
    __syncthreads();
    asm volatile("" ::: "memory");
}

// Persistent 2-layer LSTM — round-5 structure and compute path, unchanged.
__global__ __launch_bounds__(NTHR, 1) void lstm_persistent9(
    const float* __restrict__ Wih0, const float* __restrict__ Whh0,
    const float* __restrict__ bih0, const float* __restrict__ bhh0,
    const float* __restrict__ Wih1, const float* __restrict__ Whh1,
    const float* __restrict__ bih1, const float* __restrict__ bhh1,
    const _Float16* __restrict__ xT,
    _Float16* __restrict__ h0buf,   // [2][64][1024] fp16
    _Float16* __restrict__ h1buf,   // [2][64][1024] fp16
    unsigned* __restrict__ bar,
    float* __restrict__ out)        // out[64][512][1024] | hT[2][64][1024] | cT[2][64][1024]
{
    extern __shared__ __align__(16) char smem[];
    _Float16* w0x = (_Float16*)smem;        // [ 64][16][8]  K=512  (W_ih_0 slice)
    _Float16* w0h = w0x + 16 * FEAT;        // [128][16][8]  K=1024 (W_hh_0 slice)
    _Float16* w1  = w0h + 16 * HID;         // [256][16][8]  K=2048 (W_ih_1 ++ W_hh_1)
    unsigned* comm = (unsigned*)(w1 + 16 * 2048);  // [crewN, nxcd]

    const int wg  = blockIdx.x;
    const int u0  = ((wg & 7) * 32 + (wg >> 3)) * 4;  // XCD-contiguous unit blocks
    const int tid = threadIdx.x;

    // one-time XCD census (rounds 2/5 proven): exactly one slot-0 WG per XCD.
    unsigned my_xcd = 0, my_slot = 1;
    if (tid == 0) {
        unsigned* crewcnt = bar + 512;   // [16] stride 32, zero-init
        my_xcd  = __builtin_amdgcn_s_getreg(63508) & 15u;  // hwreg(HW_REG_XCC_ID=20,0,32)
        my_slot = __hip_atomic_fetch_add(crewcnt + 32 * my_xcd, 1u, __ATOMIC_RELAXED, AGENT);
    }

    // ---- one-time: convert fp32 weight slices -> fp16 LDS fragments ----
    for (int idx = tid; idx < 16 * FEAT; idx += NTHR) {
        int m = idx >> 9, k = idx & (FEAT - 1);
        int grow = (m & 3) * HID + u0 + (m >> 2);
        w0x[(((k >> 3) * 16) + m) * 8 + (k & 7)] = (_Float16)Wih0[grow * FEAT + k];
    }
    for (int idx = tid; idx < 16 * HID; idx += NTHR) {
        int m = idx >> 10, k = idx & (HID - 1);
        int grow = (m & 3) * HID + u0 + (m >> 2);
        w0h[(((k >> 3) * 16) + m) * 8 + (k & 7)] = (_Float16)Whh0[grow * HID + k];
    }
    for (int idx = tid; idx < 16 * 2048; idx += NTHR) {
        int m = idx >> 11, k = idx & 2047;
        int grow = (m & 3) * HID + u0 + (m >> 2);
        float v = (k < HID) ? Wih1[grow * HID + k] : Whh1[grow * HID + (k - HID)];
        w1[(((k >> 3) * 16) + m) * 8 + (k & 7)] = (_Float16)v;
    }

    const int lane  = tid & 63;
    const int wv    = tid >> 6;      // wave -> 16-batch tile
    const int q     = lane >> 4;     // quad: local unit (for C) / k-block (for A,B)
    const int n     = lane & 15;     // col: batch (for C/B) / row m (for A)
    const int batch = wv * 16 + n;
    const int unit  = u0 + q;

    float b0r[4], b1r[4];
#pragma unroll
    for (int r = 0; r < 4; ++r) {
        int grow = r * HID + unit;
        b0r[r] = bih0[grow] + bhh0[grow];
        b1r[r] = bih1[grow] + bhh1[grow];
    }

    __syncthreads();

    const half8_t* a0x = (const half8_t*)w0x;
    const half8_t* a0h = (const half8_t*)w0h;
    const half8_t* a1  = (const half8_t*)w1;
    const float4_t fzero = {0.f, 0.f, 0.f, 0.f};

    float c0 = 0.f, c1 = 0.f, h0v = 0.f, h1v = 0.f;
    float4_t acc[4];
    half8_t  xreg[16];

    // ---- prologue: L0(0): gates = x_0 @ Wih0^T + b   (h0_prev = 0) ----
    {
        const _Float16* xb = xT + (size_t)batch * FEAT + q * 8;
        acc[0] = fzero; acc[1] = fzero; acc[2] = fzero; acc[3] = fzero;
#pragma unroll
        for (int s = 0; s < 16; ++s)
            acc[s & 3] = __builtin_amdgcn_mfma_f32_16x16x32_f16(
                a0x[(s * 4 + q) * 16 + n], *(const half8_t*)(xb + s * 32), acc[s & 3], 0, 0, 0);
        float4_t g = (acc[0] + acc[1]) + (acc[2] + acc[3]);
        float I = sigf(g.x + b0r[0]);
        float G = tanh_fast(g.z + b0r[2]);
        float O = sigf(g.w + b0r[3]);
        c0  = I * G;                   // f * c_prev = 0
        h0v = O * tanh_fast(c0);
        h0buf[batch * HID + unit] = (_Float16)h0v;     // buffer 0 = h0(0)
    }
    {   // prefetch x(1)
        const _Float16* xb = xT + ((size_t)BATCH + batch) * FEAT + q * 8;
#pragma unroll
        for (int s = 0; s < 16; ++s) xreg[s] = *(const half8_t*)(xb + s * 32);
    }
    // step 1: full (round-5 proven) barrier; doubles as census fence
    grid_barrier_full(bar, wg & 7, 1u, my_slot, my_xcd);

    // census results (final after the full barrier): crewN, #nonempty XCDs
    if (tid == 0) {
        unsigned* crewcnt = bar + 512;
        unsigned nx = 0;
        for (int i = 0; i < 16; ++i)
            if (__hip_atomic_load(crewcnt + 32 * i, __ATOMIC_RELAXED, AGENT) > 0u) nx++;
        comm[0] = __hip_atomic_load(crewcnt + 32 * my_xcd, __ATOMIC_RELAXED, AGENT);
        comm[1] = nx;
    }
    __syncthreads();
    const unsigned crewN = comm[0];
    const unsigned nxcd  = comm[1];

    for (int t = 0; t < TSTEPS; ++t) {
        // ---- p0 = h0(t) fragments: feed L1(t) now, L0(t+1) later ----
        const _Float16* h0cur = h0buf + (t & 1) * (BATCH * HID) + batch * HID + q * 8;
        half8_t p0r[32];
#pragma unroll
        for (int s = 0; s < 32; ++s) p0r[s] = *(const half8_t*)(h0cur + s * 32);

        // ---------- layer 1: gates = h0(t)@Wih1^T + h1(t-1)@Whh1^T + b ----------
        acc[0] = fzero; acc[1] = fzero; acc[2] = fzero; acc[3] = fzero;
#pragma unroll 8
        for (int s = 0; s < 32; ++s)
            acc[s & 3] = __builtin_amdgcn_mfma_f32_16x16x32_f16(
                a1[(s * 4 + q) * 16 + n], p0r[s], acc[s & 3], 0, 0, 0);
        {
            const _Float16* p1 = h1buf + ((t & 1) ^ 1) * (BATCH * HID) + batch * HID + q * 8;
#pragma unroll 8
            for (int s = 0; s < 32; ++s)
                acc[s & 3] = __builtin_amdgcn_mfma_f32_16x16x32_f16(
                    a1[(128 + s * 4 + q) * 16 + n], *(const half8_t*)(p1 + s * 32), acc[s & 3], 0, 0, 0);
        }
        {
            float4_t g = (acc[0] + acc[1]) + (acc[2] + acc[3]);
            float I = sigf(g.x + b1r[0]);
            float F = sigf(g.y + b1r[1]);
            float G = tanh_fast(g.z + b1r[2]);
            float O = sigf(g.w + b1r[3]);
            c1  = F * c1 + I * G;
            h1v = O * tanh_fast(c1);
        }
        h1buf[(t & 1) * (BATCH * HID) + batch * HID + unit] = (_Float16)h1v;
        out[((size_t)batch * TSTEPS + t) * HID + unit] = h1v;

        if (t + 1 < TSTEPS) {
            // ---- layer 0 at t+1 — consumes xreg (x(t+1)) and p0r (h0(t)) ----
            acc[0] = fzero; acc[1] = fzero; acc[2] = fzero; acc[3] = fzero;
#pragma unroll 8
            for (int s = 0; s < 16; ++s)
                acc[s & 3] = __builtin_amdgcn_mfma_f32_16x16x32_f16(
                    a0x[(s * 4 + q) * 16 + n], xreg[s], acc[s & 3], 0, 0, 0);
#pragma unroll 8
            for (int s = 0; s < 32; ++s)
                acc[s & 3] = __builtin_amdgcn_mfma_f32_16x16x32_f16(
                    a0h[(s * 4 + q) * 16 + n], p0r[s], acc[s & 3], 0, 0, 0);
            {
                float4_t g = (acc[0] + acc[1]) + (acc[2] + acc[3]);
                float I = sigf(g.x + b0r[0]);
                float F = sigf(g.y + b0r[1]);
                float G = tanh_fast(g.z + b0r[2]);
                float O = sigf(g.w + b0r[3]);
                c0  = F * c0 + I * G;
                h0v = O * tanh_fast(c0);
            }
            h0buf[((t + 1) & 1) * (BATCH * HID) + batch * HID + unit] = (_Float16)h0v;
            // refill xreg with x(t+2) AFTER consumption; overlaps barrier wait
            if (t + 2 < TSTEPS) {
                const _Float16* xb = xT + ((size_t)(t + 2) * BATCH + batch) * FEAT + q * 8;
#pragma unroll
                for (int s = 0; s < 16; ++s) xreg[s] = *(const half8_t*)(xb + s * 32);
            }
            grid_barrier_slim(bar, (unsigned)(t + 2), my_slot, my_xcd, crewN, nxcd);
        }
    }

    float* hT = out + (size_t)BATCH * TSTEPS * HID;
    float* cT = hT + 2 * BATCH * HID;
    hT[batch * HID + unit]               = h0v;
    hT[BATCH * HID + batch * HID + unit] = h1v;
    cT[batch * HID + unit]               = c0;
    cT[BATCH * HID + batch * HID + unit] = c1;
}

extern "C" void kernel_launch(void* const* d_in, const int* in_sizes, int n_in,
                              void* d_out, int out_size, void* d_ws, size_t ws_size,
                              hipStream_t stream) {
    (void)in_sizes; (void)n_in; (void)out_size; (void)ws_size;
    const float* x    = (const float*)d_in[0];
    const float* Wih0 = (const float*)d_in[1];
    const float* Whh0 = (const float*)d_in[2];
    const float* bih0 = (const float*)d_in[3];
    const float* bhh0 = (const float*)d_in[4];
    const float* Wih1 = (const float*)d_in[5];
    const float* Whh1 = (const float*)d_in[6];
    const float* bih1 = (const float*)d_in[7];
    const float* bhh1 = (const float*)d_in[8];

    char* ws = (char*)d_ws;
    unsigned* bar   = (unsigned*)ws;                 // 64 KB barrier area
    _Float16* h0buf = (_Float16*)(ws + (64 << 10));  // 256 KB [2][64][1024]
    _Float16* h1buf = (_Float16*)(ws + (64 << 10) + (256 << 10));
    _Float16* xT    = (_Float16*)(ws + (1 << 20));   // 32 MB region (round-0 proven)

    hipMemsetAsync(d_ws, 0, 1 << 20, stream);        // zero barrier + h bufs

    xpose_kernel<<<(BATCH * TSTEPS * FEAT / 4) / NTHR, NTHR, 0, stream>>>(x, xT);

    const int shmem = 16 * (FEAT + HID + 2048) * (int)sizeof(_Float16) + 256;  // +comm
    hipFuncSetAttribute((const void*)lstm_persistent9,
                        hipFuncAttributeMaxDynamicSharedMemorySize, shmem);
    lstm_persistent9<<<NWG, NTHR, shmem, stream>>>(
        Wih0, Whh0, bih0, bhh0, Wih1, Whh1, bih1, bhh1,
        xT, h0buf, h1buf, bar, (float*)d_out);
}